// Round 11
// baseline (277.826 us; speedup 1.0000x reference)
//
#include <hip/hip_runtime.h>
#include <float.h>

#define NROWS 32768   // B*S = 8*4096
#define KDIM  512
#define NEMB  4096

#define NCB 32        // 128-wide code blocks
#define MARGIN 8.0f   // i8-score candidate margin (~6 sigma of score-err delta)
#define BIAS  1024.0f // keeps pass-1 scores positive -> float bits are uint-order-preserving
#define QSCALE 19.5384615f   // 127/6.5
#define QCLAMP 6.49f
#define QINV2  (-2.0f / (QSCALE * QSCALE))   // score = fmaf(QINV2, dot_int, nrm+BIAS)

// ---- ws layout (float units) ----
#define OFF_NORMS 0u
#define OFF_ET    4096u
#define OFF_PART  (OFF_ET + 2097152u)          // float4 top2: NROWS*NCB
#define OFF_IDX   (OFF_PART + 4194304u)        // fallback only
#define OFF_DP    (OFF_IDX + 32768u)           // 8192 partials
#define OFF_XQ8   (OFF_DP + 8192u)             // i8: NROWS*KDIM bytes = 4,194,304 floats
#define OFF_EQ8   (OFF_XQ8 + 4194304u)         // i8: NEMB*KDIM bytes  =   524,288 floats
#define WS_FAST_FLOATS (OFF_EQ8 + 524288u)     // ~44.2 MB
// ---- out layout (float units) ----
#define OUT_Q    0u
#define OUT_DIFF 16777216u
#define OUT_IDX  16777217u

typedef __attribute__((ext_vector_type(4))) int   i32x4;
typedef __attribute__((ext_vector_type(4))) float f32x4;
typedef unsigned long long ull;

static __device__ inline signed char f2q(float v) {
    v = fminf(fmaxf(v, -QCLAMP), QCLAMP);
    return (signed char)__float2int_rn(v * QSCALE);
}
static __device__ inline bool better(float s, int i, float t, int j) {
    return s < t || (s == t && i < j);
}

// ---------------- kernel 1a: norms from original e (fallback path, strided) ----------------
__global__ __launch_bounds__(256) void k_norms(const float* __restrict__ e,
                                               float* __restrict__ norms) {
    int j = blockIdx.x * 256 + threadIdx.x;
    float s = 0.f;
    for (int k = 0; k < KDIM; ++k) {
        float v = e[(size_t)k * NEMB + j];
        s += v * v;
    }
    norms[j] = s;
}

// ---------------- kernel 1b: norms from et (fast path, coalesced rows) ----------------
__global__ __launch_bounds__(256) void k_norms_et(const float* __restrict__ et,
                                                  float* __restrict__ norms) {
    int row = blockIdx.x * 4 + (threadIdx.x >> 6);
    int lane = threadIdx.x & 63;
    const float* er = et + (size_t)row * KDIM + lane * 8;
    float4 v0 = *(const float4*)er;
    float4 v1 = *(const float4*)(er + 4);
    float s = v0.x * v0.x + v0.y * v0.y + v0.z * v0.z + v0.w * v0.w
            + v1.x * v1.x + v1.y * v1.y + v1.z * v1.z + v1.w * v1.w;
#pragma unroll
    for (int off = 1; off < 64; off <<= 1) s += __shfl_xor(s, off, 64);
    if (lane == 0) norms[row] = s;
}

// ---------------- kernel 2: transpose embed + i8 quantize ----------------
__global__ void k_split_et(const float* __restrict__ e, float* __restrict__ et,
                           signed char* __restrict__ eq8) {
    __shared__ float t[32][33];
    int jb = blockIdx.x * 32, kb = blockIdx.y * 32;
    int tx = threadIdx.x, ty = threadIdx.y;
    for (int i = ty; i < 32; i += 8)
        t[i][tx] = e[(size_t)(kb + i) * NEMB + jb + tx];
    __syncthreads();
    for (int i = ty; i < 32; i += 8) {
        float v = t[tx][i];
        size_t o = (size_t)(jb + i) * KDIM + kb + tx;
        et[o] = v;
        eq8[o] = f2q(v);
    }
}

// ---------------- kernel 3: i8 quantize x ----------------
__global__ __launch_bounds__(256) void k_quant_x(const float* __restrict__ x,
                                                 signed char* __restrict__ xq8) {
    size_t i = ((size_t)blockIdx.x * 256 + threadIdx.x) * 4;
    float4 v = *(const float4*)(x + i);
    char4 q;
    q.x = f2q(v.x); q.y = f2q(v.y); q.z = f2q(v.z); q.w = f2q(v.w);
    *(char4*)(xq8 + i) = q;
}

// ---------------- kernel 4: i8 MFMA GEMM + per-128-block TOP-2 ----------------
// 4096 blocks, 256 thr = 4 waves (2 wr x 2 wc), 3 blocks/CU (launch_bounds(256,3)).
// Block order: cgrp INNER per XCD -> 16 consecutive blocks share one 64KB A-panel
// (xq8 L2-hot after first); eq8 (2MB) L2-resident. SWAPPED operands: code axis
// lane-local. mfma_i32_16x16x64_i8, 8 K-steps, dbuf, both-sides 16B-chunk swizzle.
__global__ __launch_bounds__(256, 3) void k_mfma_argmin(
        const signed char* __restrict__ xq8, const signed char* __restrict__ eq8,
        const float* __restrict__ norms, float4* __restrict__ part)
{
    __shared__ signed char As[2][128 * 64];   // x rows: 8 KB / buf
    __shared__ signed char Bs[2][256 * 64];   // codes: 16 KB / buf

    const int tid = threadIdx.x;
    const int wv = tid >> 6, ln = tid & 63;
    const int lr = ln & 15, hg = ln >> 4;
    const int wr = wv >> 1, wc = wv & 1;

    // XCD decode, cgrp-inner for A-panel L2 reuse
    const int orig = blockIdx.x;             // 0..4095
    const int xcd = orig & 7;
    const int local = orig >> 3;             // 0..511
    const int cgrp = local & 15;             // inner: 16 col groups
    const int rbl = local >> 4;              // 0..31
    const int rb = xcd * 32 + rbl;           // 0..255
    const int row0 = rb * 128, col0 = cgrp * 256;

    // staging source offsets in i8 units (swizzled 16B chunk: cg ^= (r>>1)&3)
    size_t aoff[2], boff[4];
#pragma unroll
    for (int i = 0; i < 2; ++i) {
        int slot = (i * 4 + wv) * 64 + ln;
        int r = slot >> 2;
        int cg = (slot & 3) ^ ((r >> 1) & 3);
        aoff[i] = (size_t)(row0 + r) * KDIM + cg * 16;
    }
#pragma unroll
    for (int i = 0; i < 4; ++i) {
        int slot = (i * 4 + wv) * 64 + ln;
        int r = slot >> 2;
        int cg = (slot & 3) ^ ((r >> 1) & 3);
        boff[i] = (size_t)(col0 + r) * KDIM + cg * 16;
    }

    i32x4 acc[8][4];    // [code-subtile][xrow-subtile]
#pragma unroll
    for (int m = 0; m < 8; ++m)
#pragma unroll
        for (int n = 0; n < 4; ++n) acc[m][n] = (i32x4){0, 0, 0, 0};

#define STAGE(buf, step)                                                            \
    do {                                                                            \
        int k0_ = (step) * 64;                                                      \
        _Pragma("unroll")                                                           \
        for (int i_ = 0; i_ < 2; ++i_)                                              \
            __builtin_amdgcn_global_load_lds(                                       \
                (const __attribute__((address_space(1))) void*)(xq8 + aoff[i_] + k0_), \
                (__attribute__((address_space(3))) void*)&As[buf][(i_ * 4 + wv) * 1024], \
                16, 0, 0);                                                          \
        _Pragma("unroll")                                                           \
        for (int i_ = 0; i_ < 4; ++i_)                                              \
            __builtin_amdgcn_global_load_lds(                                       \
                (const __attribute__((address_space(1))) void*)(eq8 + boff[i_] + k0_), \
                (__attribute__((address_space(3))) void*)&Bs[buf][(i_ * 4 + wv) * 1024], \
                16, 0, 0);                                                          \
    } while (0)

    STAGE(0, 0);
    __syncthreads();
    int cur = 0;
    const int swzB = (hg ^ ((lr >> 1) & 3)) * 16;   // byte offset within 64B row
    for (int step = 0; step < 8; ++step) {
        if (step < 7) STAGE(cur ^ 1, step + 1);
        i32x4 a[8], b[4];
#pragma unroll
        for (int m = 0; m < 8; ++m)     // A-frags = codes (from Bs)
            a[m] = *(const i32x4*)&Bs[cur][(wc * 128 + m * 16 + lr) * 64 + swzB];
#pragma unroll
        for (int n = 0; n < 4; ++n)     // B-frags = x rows (from As)
            b[n] = *(const i32x4*)&As[cur][(wr * 64 + n * 16 + lr) * 64 + swzB];
#pragma unroll
        for (int m = 0; m < 8; ++m)
#pragma unroll
            for (int n = 0; n < 4; ++n)
                acc[m][n] = __builtin_amdgcn_mfma_i32_16x16x64_i8(a[m], b[n], acc[m][n], 0, 0, 0);
        __syncthreads();
        cur ^= 1;
    }
#undef STAGE

    // epilogue A: convert i32 dot -> biased float score (per-m norms: 4 live regs)
    const int colbase = col0 + wc * 128;
    const int cbw = cgrp * 2 + wc;
    f32x4 sc[8][4];
#pragma unroll
    for (int m = 0; m < 8; ++m) {
        float nr[4];
#pragma unroll
        for (int r = 0; r < 4; ++r)
            nr[r] = norms[colbase + m * 16 + hg * 4 + r] + BIAS;
#pragma unroll
        for (int n = 0; n < 4; ++n)
#pragma unroll
            for (int r = 0; r < 4; ++r)
                sc[m][n][r] = fmaf(QINV2, (float)acc[m][n][r], nr[r]);   // > 0 by BIAS
    }

    // epilogue B: per-xrow TOP-2 over 128 codes (32 lane-local + 2-step hg butterfly)
#pragma unroll
    for (int n = 0; n < 4; ++n) {
        ull k0 = ~0ull, k1 = ~0ull;
#pragma unroll
        for (int m = 0; m < 8; ++m)
#pragma unroll
            for (int r = 0; r < 4; ++r) {
                ull key = ((ull)__float_as_uint(sc[m][n][r]) << 32)
                        | (unsigned)(colbase + m * 16 + hg * 4 + r);
                if (key < k0) { k1 = k0; k0 = key; }
                else if (key < k1) { k1 = key; }
            }
#pragma unroll
        for (int off = 16; off < 64; off <<= 1) {   // butterfly over hg only
            ull o0 = __shfl_xor(k0, off, 64);
            ull o1 = __shfl_xor(k1, off, 64);
            ull mx = k0 > o0 ? k0 : o0;
            ull mn = k1 < o1 ? k1 : o1;
            k0 = k0 < o0 ? k0 : o0;
            k1 = mx < mn ? mx : mn;
        }
        if (hg == 0) {
            int row_out = row0 + wr * 64 + n * 16 + lr;
            part[(size_t)row_out * NCB + cbw] =
                make_float4(__uint_as_float((unsigned)(k0 >> 32)),
                            __int_as_float((int)(k0 & 0xFFFFFFFFu)),
                            __uint_as_float((unsigned)(k1 >> 32)),
                            __int_as_float((int)(k1 & 0xFFFFFFFFu)));
        }
    }
}

// ---------------- kernel 5: fused exact refine + quantize gather + diff partial ----------------
__global__ __launch_bounds__(256) void k_refine(const float* __restrict__ x,
                                                const float* __restrict__ et,
                                                const float* __restrict__ norms,
                                                const float4* __restrict__ part,
                                                float* __restrict__ out,
                                                float* __restrict__ dpart) {
    const int row = blockIdx.x * 4 + (threadIdx.x >> 6);
    const int lane = threadIdx.x & 63;

    float xv[8];
    *(float4*)&xv[0] = *(const float4*)(x + (size_t)row * KDIM + lane * 8);
    *(float4*)&xv[4] = *(const float4*)(x + (size_t)row * KDIM + lane * 8 + 4);

    const float4* prow = part + (size_t)row * NCB;
    float m = FLT_MAX;
    for (int cbi = 0; cbi < NCB; ++cbi) m = fminf(m, prow[cbi].x);
    const float thr = m + MARGIN;

    int cnt = 0, only = 0x7FFFFFFF;
    for (int cbi = 0; cbi < NCB; ++cbi) {
        float4 p = prow[cbi];
        if (p.x <= thr) { ++cnt; only = __float_as_int(p.y); }
        if (p.z <= thr) { ++cnt; only = __float_as_int(p.w); }
    }

    int bj;
    if (cnt == 1) {
        bj = only;                                 // unambiguous winner, skip rescoring
    } else {
        float bs = FLT_MAX;
        bj = 0x7FFFFFFF;
        for (int cbi = 0; cbi < NCB; ++cbi) {
            float4 p = prow[cbi];
#pragma unroll
            for (int t = 0; t < 2; ++t) {
                float sh = t ? p.z : p.x;
                int j = __float_as_int(t ? p.w : p.y);
                if (sh <= thr) {                   // wave-uniform branch
                    const float* er = et + (size_t)j * KDIM + lane * 8;
                    float ev[8];
                    *(float4*)&ev[0] = *(const float4*)er;
                    *(float4*)&ev[4] = *(const float4*)(er + 4);
                    float d = 0.f;
#pragma unroll
                    for (int q = 0; q < 8; ++q) d += xv[q] * ev[q];
#pragma unroll
                    for (int off = 1; off < 64; off <<= 1) d += __shfl_xor(d, off, 64);
                    float s = norms[j] - 2.f * d;  // exact fp32 score
                    if (better(s, j, bs, bj)) { bs = s; bj = j; }
                }
            }
        }
    }

    // winner: write quantize row + diff partial
    const float* er = et + (size_t)bj * KDIM + lane * 8;
    float ev[8];
    *(float4*)&ev[0] = *(const float4*)er;
    *(float4*)&ev[4] = *(const float4*)(er + 4);
    float dsum = 0.f;
#pragma unroll
    for (int q = 0; q < 8; ++q) {
        float d = ev[q] - xv[q];
        dsum += d * d;
    }
    *(float4*)(out + OUT_Q + (size_t)row * KDIM + lane * 8) = *(float4*)&ev[0];
    *(float4*)(out + OUT_Q + (size_t)row * KDIM + lane * 8 + 4) = *(float4*)&ev[4];
#pragma unroll
    for (int off = 1; off < 64; off <<= 1) dsum += __shfl_xor(dsum, off, 64);

    __shared__ float ds4[4];
    if (lane == 0) {
        out[OUT_IDX + row] = (float)bj;
        ds4[threadIdx.x >> 6] = dsum;
    }
    __syncthreads();
    if (threadIdx.x == 0)
        dpart[blockIdx.x] = ds4[0] + ds4[1] + ds4[2] + ds4[3];
}

// ---------------- fallback fp32 GEMM-argmin (ws-lean, round-1) ----------------
#define TMF 128
#define TNF 128
#define TKF 16
__global__ __launch_bounds__(256) void k_gemm_argmin(
        const float* __restrict__ x, const float* __restrict__ e,
        const float* __restrict__ norms, float2* __restrict__ part)
{
    __shared__ float xs[TKF][132];
    __shared__ float es[TKF][TNF];
    __shared__ float2 red[TMF][16];

    const int row0 = blockIdx.x * TMF, col0 = blockIdx.y * TNF;
    const int tid = threadIdx.x;
    const int ty = tid >> 4, tx = tid & 15;

    float acc[8][8];
#pragma unroll
    for (int i = 0; i < 8; ++i)
#pragma unroll
        for (int j = 0; j < 8; ++j) acc[i][j] = 0.f;

    for (int k0 = 0; k0 < KDIM; k0 += TKF) {
        __syncthreads();
#pragma unroll
        for (int s = 0; s < 2; ++s) {
            int slot = tid + s * 256;
            int r = slot >> 2, c4 = slot & 3;
            float4 v = *(const float4*)(x + (size_t)(row0 + r) * KDIM + k0 + c4 * 4);
            xs[c4 * 4 + 0][r] = v.x; xs[c4 * 4 + 1][r] = v.y;
            xs[c4 * 4 + 2][r] = v.z; xs[c4 * 4 + 3][r] = v.w;
        }
#pragma unroll
        for (int s = 0; s < 2; ++s) {
            int slot = tid + s * 256;
            int k = slot >> 5, c4 = slot & 31;
            *(float4*)(&es[k][c4 * 4]) =
                *(const float4*)(e + (size_t)(k0 + k) * NEMB + col0 + c4 * 4);
        }
        __syncthreads();
#pragma unroll
        for (int k = 0; k < TKF; ++k) {
            float xv[8], ev[8];
            *(float4*)&xv[0] = *(const float4*)&xs[k][ty * 8];
            *(float4*)&xv[4] = *(const float4*)&xs[k][ty * 8 + 4];
            *(float4*)&ev[0] = *(const float4*)&es[k][tx * 8];
            *(float4*)&ev[4] = *(const float4*)&es[k][tx * 8 + 4];
#pragma unroll
            for (int i = 0; i < 8; ++i)
#pragma unroll
                for (int j = 0; j < 8; ++j) acc[i][j] += xv[i] * ev[j];
        }
    }
    float nrm[8];
#pragma unroll
    for (int j = 0; j < 8; ++j) nrm[j] = norms[col0 + tx * 8 + j];
#pragma unroll
    for (int i = 0; i < 8; ++i) {
        float best = FLT_MAX; int bj = 0;
#pragma unroll
        for (int j = 0; j < 8; ++j) {
            float sc = nrm[j] - 2.f * acc[i][j];
            if (sc < best) { best = sc; bj = tx * 8 + j; }
        }
        red[ty * 8 + i][tx] = make_float2(best, __int_as_float(bj));
    }
    __syncthreads();
    if (tid < TMF) {
        float best = FLT_MAX; int bj = 0;
        for (int t = 0; t < 16; ++t) {
            float2 p = red[tid][t];
            if (p.x < best) { best = p.x; bj = __float_as_int(p.y); }
        }
        part[(size_t)(row0 + tid) * NCB + blockIdx.y] =
            make_float2(best, __int_as_float(col0 + bj));
    }
}

__global__ void k_transpose(const float* __restrict__ e, float* __restrict__ et) {
    __shared__ float t[32][33];
    int jb = blockIdx.x * 32, kb = blockIdx.y * 32;
    int tx = threadIdx.x, ty = threadIdx.y;
    for (int i = ty; i < 32; i += 8)
        t[i][tx] = e[(size_t)(kb + i) * NEMB + jb + tx];
    __syncthreads();
    for (int i = ty; i < 32; i += 8)
        et[(size_t)(jb + i) * KDIM + kb + tx] = t[tx][i];
}

__global__ __launch_bounds__(256) void k_reduce(const float2* __restrict__ part,
                                                int* __restrict__ idx_out,
                                                float* __restrict__ out) {
    int row = blockIdx.x * 256 + threadIdx.x;
    float best = FLT_MAX;
    int bj = 0x7FFFFFFF;
    for (int cbi = 0; cbi < NCB; ++cbi) {
        float2 p = part[(size_t)row * NCB + cbi];
        int c = __float_as_int(p.y);
        if (p.x < best || (p.x == best && c < bj)) { best = p.x; bj = c; }
    }
    idx_out[row] = bj;
    out[OUT_IDX + row] = (float)bj;
}

__global__ __launch_bounds__(256) void k_gather(const float* __restrict__ x,
                                                const float* __restrict__ et,
                                                const int* __restrict__ idx,
                                                float* __restrict__ out,
                                                float* __restrict__ dpart) {
    const int b = blockIdx.x;
    const int tid = threadIdx.x;
    const int row0 = b * 16;
    float s = 0.f;
    for (int i = tid; i < 16 * KDIM; i += 256) {
        int r = i >> 9;
        int k = i & (KDIM - 1);
        int row = row0 + r;
        float q = et[(size_t)idx[row] * KDIM + k];
        float xv = x[(size_t)row * KDIM + k];
        float d = q - xv;
        s += d * d;
        out[OUT_Q + (size_t)row * KDIM + k] = q;
    }
#pragma unroll
    for (int off = 32; off >= 1; off >>= 1) s += __shfl_down(s, off, 64);
    __shared__ float ws_[4];
    int lane = tid & 63, wvi = tid >> 6;
    if (lane == 0) ws_[wvi] = s;
    __syncthreads();
    if (tid == 0) dpart[b] = ws_[0] + ws_[1] + ws_[2] + ws_[3];
}

// ---------------- final diff over n partials ----------------
__global__ __launch_bounds__(256) void k_diff(const float* __restrict__ dpart, int n,
                                              float* __restrict__ out) {
    int tid = threadIdx.x;
    float s = 0.f;
    for (int i = tid; i < n; i += 256) s += dpart[i];
#pragma unroll
    for (int off = 32; off >= 1; off >>= 1) s += __shfl_down(s, off, 64);
    __shared__ float ws_[4];
    int lane = tid & 63, wvi = tid >> 6;
    if (lane == 0) ws_[wvi] = s;
    __syncthreads();
    if (tid == 0) out[OUT_DIFF] = (ws_[0] + ws_[1] + ws_[2] + ws_[3]) / 16777216.f;
}

extern "C" void kernel_launch(void* const* d_in, const int* in_sizes, int n_in,
                              void* d_out, int out_size, void* d_ws, size_t ws_size,
                              hipStream_t stream) {
    const float* x = (const float*)d_in[0];   // [8,4096,512]
    const float* e = (const float*)d_in[1];   // [512,4096]
    float* out = (float*)d_out;
    float* ws = (float*)d_ws;

    float*  norms = ws + OFF_NORMS;
    float*  et    = ws + OFF_ET;
    float*  dpart = ws + OFF_DP;

    if (ws_size >= (size_t)WS_FAST_FLOATS * 4) {
        float4* part = (float4*)(ws + OFF_PART);
        signed char* xq8 = (signed char*)(ws + OFF_XQ8);
        signed char* eq8 = (signed char*)(ws + OFF_EQ8);
        k_split_et<<<dim3(NEMB / 32, KDIM / 32), dim3(32, 8), 0, stream>>>(e, et, eq8);
        k_norms_et<<<NEMB / 4, 256, 0, stream>>>(et, norms);
        k_quant_x<<<(NROWS * KDIM) / (256 * 4), 256, 0, stream>>>(x, xq8);
        k_mfma_argmin<<<4096, 256, 0, stream>>>(xq8, eq8, norms, part);
        k_refine<<<NROWS / 4, 256, 0, stream>>>(x, et, norms, part, out, dpart);
        k_diff<<<1, 256, 0, stream>>>(dpart, NROWS / 4, out);
    } else {
        float2* part2 = (float2*)(ws + OFF_PART);
        int* idx = (int*)(ws + OFF_IDX);
        k_norms<<<NEMB / 256, 256, 0, stream>>>(e, norms);
        k_transpose<<<dim3(NEMB / 32, KDIM / 32), dim3(32, 8), 0, stream>>>(e, et);
        k_gemm_argmin<<<dim3(NROWS / TMF, NEMB / TNF), 256, 0, stream>>>(x, e, norms, part2);
        k_reduce<<<NROWS / 256, 256, 0, stream>>>(part2, idx, out);
        k_gather<<<NROWS / 16, 256, 0, stream>>>(x, et, idx, out, dpart);
        k_diff<<<1, 256, 0, stream>>>(dpart, NROWS / 16, out);
    }
}

// Round 12
// 244.879 us; speedup vs baseline: 1.1345x; 1.1345x over previous
//
#include <hip/hip_runtime.h>
#include <float.h>

#define NROWS 32768   // B*S = 8*4096
#define KDIM  512
#define NEMB  4096

#define NCB 32        // 128-wide code blocks
#define MARGIN 8.0f   // i8-score candidate margin (~6 sigma of score-err delta)
#define BIAS  1024.0f // keeps pass-1 scores positive -> float bits are uint-order-preserving
#define QSCALE 19.5384615f   // 127/6.5
#define QCLAMP 6.49f
#define QINV2  (-2.0f / (QSCALE * QSCALE))   // score = fmaf(QINV2, dot_int, nrm+BIAS)

// ---- ws layout (float units) ----
#define OFF_NORMS 0u
#define OFF_ET    4096u
#define OFF_PART  (OFF_ET + 2097152u)          // float4 top2: NROWS*NCB
#define OFF_IDX   (OFF_PART + 4194304u)        // fallback only
#define OFF_DP    (OFF_IDX + 32768u)           // 8192 partials
#define OFF_XQ8   (OFF_DP + 8192u)             // i8: NROWS*KDIM bytes = 4,194,304 floats
#define OFF_EQ8   (OFF_XQ8 + 4194304u)         // i8: NEMB*KDIM bytes  =   524,288 floats
#define WS_FAST_FLOATS (OFF_EQ8 + 524288u)     // ~44.2 MB
// ---- out layout (float units) ----
#define OUT_Q    0u
#define OUT_DIFF 16777216u
#define OUT_IDX  16777217u

typedef __attribute__((ext_vector_type(4))) int   i32x4;
typedef __attribute__((ext_vector_type(4))) float f32x4;
typedef unsigned long long ull;

static __device__ inline signed char f2q(float v) {
    v = fminf(fmaxf(v, -QCLAMP), QCLAMP);
    return (signed char)__float2int_rn(v * QSCALE);
}
static __device__ inline bool better(float s, int i, float t, int j) {
    return s < t || (s == t && i < j);
}

// ---------------- kernel 1a: norms from original e (fallback path, strided) ----------------
__global__ __launch_bounds__(256) void k_norms(const float* __restrict__ e,
                                               float* __restrict__ norms) {
    int j = blockIdx.x * 256 + threadIdx.x;
    float s = 0.f;
    for (int k = 0; k < KDIM; ++k) {
        float v = e[(size_t)k * NEMB + j];
        s += v * v;
    }
    norms[j] = s;
}

// ---------------- kernel 1b: norms from et (fast path, coalesced rows) ----------------
__global__ __launch_bounds__(256) void k_norms_et(const float* __restrict__ et,
                                                  float* __restrict__ norms) {
    int row = blockIdx.x * 4 + (threadIdx.x >> 6);
    int lane = threadIdx.x & 63;
    const float* er = et + (size_t)row * KDIM + lane * 8;
    float4 v0 = *(const float4*)er;
    float4 v1 = *(const float4*)(er + 4);
    float s = v0.x * v0.x + v0.y * v0.y + v0.z * v0.z + v0.w * v0.w
            + v1.x * v1.x + v1.y * v1.y + v1.z * v1.z + v1.w * v1.w;
#pragma unroll
    for (int off = 1; off < 64; off <<= 1) s += __shfl_xor(s, off, 64);
    if (lane == 0) norms[row] = s;
}

// ---------------- kernel 2: transpose embed + i8 quantize ----------------
__global__ void k_split_et(const float* __restrict__ e, float* __restrict__ et,
                           signed char* __restrict__ eq8) {
    __shared__ float t[32][33];
    int jb = blockIdx.x * 32, kb = blockIdx.y * 32;
    int tx = threadIdx.x, ty = threadIdx.y;
    for (int i = ty; i < 32; i += 8)
        t[i][tx] = e[(size_t)(kb + i) * NEMB + jb + tx];
    __syncthreads();
    for (int i = ty; i < 32; i += 8) {
        float v = t[tx][i];
        size_t o = (size_t)(jb + i) * KDIM + kb + tx;
        et[o] = v;
        eq8[o] = f2q(v);
    }
}

// ---------------- kernel 3: i8 quantize x ----------------
__global__ __launch_bounds__(256) void k_quant_x(const float* __restrict__ x,
                                                 signed char* __restrict__ xq8) {
    size_t i = ((size_t)blockIdx.x * 256 + threadIdx.x) * 4;
    float4 v = *(const float4*)(x + i);
    char4 q;
    q.x = f2q(v.x); q.y = f2q(v.y); q.z = f2q(v.z); q.w = f2q(v.w);
    *(char4*)(xq8 + i) = q;
}

// ---------------- kernel 4: i8 MFMA GEMM + per-128-block TOP-2 ----------------
// 4096 blocks (round-10 XCD supertiles), 256 thr = 4 waves (2 wr x 2 wc), 2 blocks/CU.
// SWAPPED operands: code axis lane-local (32 codes/lane). mfma_i32_16x16x64_i8,
// 8 K-steps, dbuf, both-sides 16B-chunk swizzle.
// Epilogue: IN-PLACE score transform bit-cast into acc (round-9 pattern) — the
// separate sc[8][4] array in rounds 10/11 spilled to scratch (WRITE 211->346 MB).
__global__ __launch_bounds__(256, 2) void k_mfma_argmin(
        const signed char* __restrict__ xq8, const signed char* __restrict__ eq8,
        const float* __restrict__ norms, float4* __restrict__ part)
{
    __shared__ signed char As[2][128 * 64];   // x rows: 8 KB / buf
    __shared__ signed char Bs[2][256 * 64];   // codes: 16 KB / buf

    const int tid = threadIdx.x;
    const int wv = tid >> 6, ln = tid & 63;
    const int lr = ln & 15, hg = ln >> 4;
    const int wr = wv >> 1, wc = wv & 1;

    // XCD-aware supertile decode (round-10): 8 XCDs x [4 rb-bands x (8 rb x 4 cgrp)]
    const int orig = blockIdx.x;             // 0..4095
    const int xcd = orig & 7;
    const int local = orig >> 3;             // 0..511
    const int srow = local & 7;
    const int scol = (local >> 3) & 3;
    const int sblk = local >> 5;             // 0..15
    const int rb = xcd * 32 + (sblk >> 2) * 8 + srow;   // 0..255
    const int cgrp = (sblk & 3) * 4 + scol;             // 0..15
    const int row0 = rb * 128, col0 = cgrp * 256;

    // staging source offsets in i8 units (swizzled 16B chunk: cg ^= (r>>1)&3)
    size_t aoff[2], boff[4];
#pragma unroll
    for (int i = 0; i < 2; ++i) {
        int slot = (i * 4 + wv) * 64 + ln;
        int r = slot >> 2;
        int cg = (slot & 3) ^ ((r >> 1) & 3);
        aoff[i] = (size_t)(row0 + r) * KDIM + cg * 16;
    }
#pragma unroll
    for (int i = 0; i < 4; ++i) {
        int slot = (i * 4 + wv) * 64 + ln;
        int r = slot >> 2;
        int cg = (slot & 3) ^ ((r >> 1) & 3);
        boff[i] = (size_t)(col0 + r) * KDIM + cg * 16;
    }

    i32x4 acc[8][4];    // [code-subtile][xrow-subtile]
#pragma unroll
    for (int m = 0; m < 8; ++m)
#pragma unroll
        for (int n = 0; n < 4; ++n) acc[m][n] = (i32x4){0, 0, 0, 0};

#define STAGE(buf, step)                                                            \
    do {                                                                            \
        int k0_ = (step) * 64;                                                      \
        _Pragma("unroll")                                                           \
        for (int i_ = 0; i_ < 2; ++i_)                                              \
            __builtin_amdgcn_global_load_lds(                                       \
                (const __attribute__((address_space(1))) void*)(xq8 + aoff[i_] + k0_), \
                (__attribute__((address_space(3))) void*)&As[buf][(i_ * 4 + wv) * 1024], \
                16, 0, 0);                                                          \
        _Pragma("unroll")                                                           \
        for (int i_ = 0; i_ < 4; ++i_)                                              \
            __builtin_amdgcn_global_load_lds(                                       \
                (const __attribute__((address_space(1))) void*)(eq8 + boff[i_] + k0_), \
                (__attribute__((address_space(3))) void*)&Bs[buf][(i_ * 4 + wv) * 1024], \
                16, 0, 0);                                                          \
    } while (0)

    STAGE(0, 0);
    __syncthreads();
    int cur = 0;
    const int swzB = (hg ^ ((lr >> 1) & 3)) * 16;   // byte offset within 64B row
    for (int step = 0; step < 8; ++step) {
        if (step < 7) STAGE(cur ^ 1, step + 1);
        i32x4 a[8], b[4];
#pragma unroll
        for (int m = 0; m < 8; ++m)     // A-frags = codes (from Bs)
            a[m] = *(const i32x4*)&Bs[cur][(wc * 128 + m * 16 + lr) * 64 + swzB];
#pragma unroll
        for (int n = 0; n < 4; ++n)     // B-frags = x rows (from As)
            b[n] = *(const i32x4*)&As[cur][(wr * 64 + n * 16 + lr) * 64 + swzB];
#pragma unroll
        for (int m = 0; m < 8; ++m)
#pragma unroll
            for (int n = 0; n < 4; ++n)
                acc[m][n] = __builtin_amdgcn_mfma_i32_16x16x64_i8(a[m], b[n], acc[m][n], 0, 0, 0);
        __syncthreads();
        cur ^= 1;
    }
#undef STAGE

    // epilogue A: IN-PLACE i32 dot -> biased positive score bits (per-m norms: 4 live regs)
    const int colbase = col0 + wc * 128;
    const int cbw = cgrp * 2 + wc;
#pragma unroll
    for (int m = 0; m < 8; ++m) {
        float nr[4];
#pragma unroll
        for (int r = 0; r < 4; ++r)
            nr[r] = norms[colbase + m * 16 + hg * 4 + r] + BIAS;
#pragma unroll
        for (int n = 0; n < 4; ++n)
#pragma unroll
            for (int r = 0; r < 4; ++r)
                acc[m][n][r] = (int)__float_as_uint(
                    fmaf(QINV2, (float)acc[m][n][r], nr[r]));   // > 0 by BIAS
    }

    // epilogue B: per-xrow TOP-2 over 128 codes (keys straight from acc bits)
#pragma unroll
    for (int n = 0; n < 4; ++n) {
        ull k0 = ~0ull, k1 = ~0ull;
#pragma unroll
        for (int m = 0; m < 8; ++m)
#pragma unroll
            for (int r = 0; r < 4; ++r) {
                ull key = ((ull)(unsigned)acc[m][n][r] << 32)
                        | (unsigned)(colbase + m * 16 + hg * 4 + r);
                if (key < k0) { k1 = k0; k0 = key; }
                else if (key < k1) { k1 = key; }
            }
#pragma unroll
        for (int off = 16; off < 64; off <<= 1) {   // butterfly over hg only
            ull o0 = __shfl_xor(k0, off, 64);
            ull o1 = __shfl_xor(k1, off, 64);
            ull mx = k0 > o0 ? k0 : o0;
            ull mn = k1 < o1 ? k1 : o1;
            k0 = k0 < o0 ? k0 : o0;
            k1 = mx < mn ? mx : mn;
        }
        if (hg == 0) {
            int row_out = row0 + wr * 64 + n * 16 + lr;
            part[(size_t)row_out * NCB + cbw] =
                make_float4(__uint_as_float((unsigned)(k0 >> 32)),
                            __int_as_float((int)(k0 & 0xFFFFFFFFu)),
                            __uint_as_float((unsigned)(k1 >> 32)),
                            __int_as_float((int)(k1 & 0xFFFFFFFFu)));
        }
    }
}

// ---------------- kernel 5: fused exact refine + quantize gather + diff partial ----------------
__global__ __launch_bounds__(256) void k_refine(const float* __restrict__ x,
                                                const float* __restrict__ et,
                                                const float* __restrict__ norms,
                                                const float4* __restrict__ part,
                                                float* __restrict__ out,
                                                float* __restrict__ dpart) {
    const int row = blockIdx.x * 4 + (threadIdx.x >> 6);
    const int lane = threadIdx.x & 63;

    float xv[8];
    *(float4*)&xv[0] = *(const float4*)(x + (size_t)row * KDIM + lane * 8);
    *(float4*)&xv[4] = *(const float4*)(x + (size_t)row * KDIM + lane * 8 + 4);

    const float4* prow = part + (size_t)row * NCB;
    float m = FLT_MAX;
    for (int cbi = 0; cbi < NCB; ++cbi) m = fminf(m, prow[cbi].x);
    const float thr = m + MARGIN;

    int cnt = 0, only = 0x7FFFFFFF;
    for (int cbi = 0; cbi < NCB; ++cbi) {
        float4 p = prow[cbi];
        if (p.x <= thr) { ++cnt; only = __float_as_int(p.y); }
        if (p.z <= thr) { ++cnt; only = __float_as_int(p.w); }
    }

    int bj;
    if (cnt == 1) {
        bj = only;                                 // unambiguous winner, skip rescoring
    } else {
        float bs = FLT_MAX;
        bj = 0x7FFFFFFF;
        for (int cbi = 0; cbi < NCB; ++cbi) {
            float4 p = prow[cbi];
#pragma unroll
            for (int t = 0; t < 2; ++t) {
                float sh = t ? p.z : p.x;
                int j = __float_as_int(t ? p.w : p.y);
                if (sh <= thr) {                   // wave-uniform branch
                    const float* er = et + (size_t)j * KDIM + lane * 8;
                    float ev[8];
                    *(float4*)&ev[0] = *(const float4*)er;
                    *(float4*)&ev[4] = *(const float4*)(er + 4);
                    float d = 0.f;
#pragma unroll
                    for (int q = 0; q < 8; ++q) d += xv[q] * ev[q];
#pragma unroll
                    for (int off = 1; off < 64; off <<= 1) d += __shfl_xor(d, off, 64);
                    float s = norms[j] - 2.f * d;  // exact fp32 score
                    if (better(s, j, bs, bj)) { bs = s; bj = j; }
                }
            }
        }
    }

    // winner: write quantize row + diff partial
    const float* er = et + (size_t)bj * KDIM + lane * 8;
    float ev[8];
    *(float4*)&ev[0] = *(const float4*)er;
    *(float4*)&ev[4] = *(const float4*)(er + 4);
    float dsum = 0.f;
#pragma unroll
    for (int q = 0; q < 8; ++q) {
        float d = ev[q] - xv[q];
        dsum += d * d;
    }
    *(float4*)(out + OUT_Q + (size_t)row * KDIM + lane * 8) = *(float4*)&ev[0];
    *(float4*)(out + OUT_Q + (size_t)row * KDIM + lane * 8 + 4) = *(float4*)&ev[4];
#pragma unroll
    for (int off = 1; off < 64; off <<= 1) dsum += __shfl_xor(dsum, off, 64);

    __shared__ float ds4[4];
    if (lane == 0) {
        out[OUT_IDX + row] = (float)bj;
        ds4[threadIdx.x >> 6] = dsum;
    }
    __syncthreads();
    if (threadIdx.x == 0)
        dpart[blockIdx.x] = ds4[0] + ds4[1] + ds4[2] + ds4[3];
}

// ---------------- fallback fp32 GEMM-argmin (ws-lean, round-1) ----------------
#define TMF 128
#define TNF 128
#define TKF 16
__global__ __launch_bounds__(256) void k_gemm_argmin(
        const float* __restrict__ x, const float* __restrict__ e,
        const float* __restrict__ norms, float2* __restrict__ part)
{
    __shared__ float xs[TKF][132];
    __shared__ float es[TKF][TNF];
    __shared__ float2 red[TMF][16];

    const int row0 = blockIdx.x * TMF, col0 = blockIdx.y * TNF;
    const int tid = threadIdx.x;
    const int ty = tid >> 4, tx = tid & 15;

    float acc[8][8];
#pragma unroll
    for (int i = 0; i < 8; ++i)
#pragma unroll
        for (int j = 0; j < 8; ++j) acc[i][j] = 0.f;

    for (int k0 = 0; k0 < KDIM; k0 += TKF) {
        __syncthreads();
#pragma unroll
        for (int s = 0; s < 2; ++s) {
            int slot = tid + s * 256;
            int r = slot >> 2, c4 = slot & 3;
            float4 v = *(const float4*)(x + (size_t)(row0 + r) * KDIM + k0 + c4 * 4);
            xs[c4 * 4 + 0][r] = v.x; xs[c4 * 4 + 1][r] = v.y;
            xs[c4 * 4 + 2][r] = v.z; xs[c4 * 4 + 3][r] = v.w;
        }
#pragma unroll
        for (int s = 0; s < 2; ++s) {
            int slot = tid + s * 256;
            int k = slot >> 5, c4 = slot & 31;
            *(float4*)(&es[k][c4 * 4]) =
                *(const float4*)(e + (size_t)(k0 + k) * NEMB + col0 + c4 * 4);
        }
        __syncthreads();
#pragma unroll
        for (int k = 0; k < TKF; ++k) {
            float xv[8], ev[8];
            *(float4*)&xv[0] = *(const float4*)&xs[k][ty * 8];
            *(float4*)&xv[4] = *(const float4*)&xs[k][ty * 8 + 4];
            *(float4*)&ev[0] = *(const float4*)&es[k][tx * 8];
            *(float4*)&ev[4] = *(const float4*)&es[k][tx * 8 + 4];
#pragma unroll
            for (int i = 0; i < 8; ++i)
#pragma unroll
                for (int j = 0; j < 8; ++j) acc[i][j] += xv[i] * ev[j];
        }
    }
    float nrm[8];
#pragma unroll
    for (int j = 0; j < 8; ++j) nrm[j] = norms[col0 + tx * 8 + j];
#pragma unroll
    for (int i = 0; i < 8; ++i) {
        float best = FLT_MAX; int bj = 0;
#pragma unroll
        for (int j = 0; j < 8; ++j) {
            float sc = nrm[j] - 2.f * acc[i][j];
            if (sc < best) { best = sc; bj = tx * 8 + j; }
        }
        red[ty * 8 + i][tx] = make_float2(best, __int_as_float(bj));
    }
    __syncthreads();
    if (tid < TMF) {
        float best = FLT_MAX; int bj = 0;
        for (int t = 0; t < 16; ++t) {
            float2 p = red[tid][t];
            if (p.x < best) { best = p.x; bj = __float_as_int(p.y); }
        }
        part[(size_t)(row0 + tid) * NCB + blockIdx.y] =
            make_float2(best, __int_as_float(col0 + bj));
    }
}

__global__ void k_transpose(const float* __restrict__ e, float* __restrict__ et) {
    __shared__ float t[32][33];
    int jb = blockIdx.x * 32, kb = blockIdx.y * 32;
    int tx = threadIdx.x, ty = threadIdx.y;
    for (int i = ty; i < 32; i += 8)
        t[i][tx] = e[(size_t)(kb + i) * NEMB + jb + tx];
    __syncthreads();
    for (int i = ty; i < 32; i += 8)
        et[(size_t)(jb + i) * KDIM + kb + tx] = t[tx][i];
}

__global__ __launch_bounds__(256) void k_reduce(const float2* __restrict__ part,
                                                int* __restrict__ idx_out,
                                                float* __restrict__ out) {
    int row = blockIdx.x * 256 + threadIdx.x;
    float best = FLT_MAX;
    int bj = 0x7FFFFFFF;
    for (int cbi = 0; cbi < NCB; ++cbi) {
        float2 p = part[(size_t)row * NCB + cbi];
        int c = __float_as_int(p.y);
        if (p.x < best || (p.x == best && c < bj)) { best = p.x; bj = c; }
    }
    idx_out[row] = bj;
    out[OUT_IDX + row] = (float)bj;
}

__global__ __launch_bounds__(256) void k_gather(const float* __restrict__ x,
                                                const float* __restrict__ et,
                                                const int* __restrict__ idx,
                                                float* __restrict__ out,
                                                float* __restrict__ dpart) {
    const int b = blockIdx.x;
    const int tid = threadIdx.x;
    const int row0 = b * 16;
    float s = 0.f;
    for (int i = tid; i < 16 * KDIM; i += 256) {
        int r = i >> 9;
        int k = i & (KDIM - 1);
        int row = row0 + r;
        float q = et[(size_t)idx[row] * KDIM + k];
        float xv = x[(size_t)row * KDIM + k];
        float d = q - xv;
        s += d * d;
        out[OUT_Q + (size_t)row * KDIM + k] = q;
    }
#pragma unroll
    for (int off = 32; off >= 1; off >>= 1) s += __shfl_down(s, off, 64);
    __shared__ float ws_[4];
    int lane = tid & 63, wvi = tid >> 6;
    if (lane == 0) ws_[wvi] = s;
    __syncthreads();
    if (tid == 0) dpart[b] = ws_[0] + ws_[1] + ws_[2] + ws_[3];
}

// ---------------- final diff over n partials ----------------
__global__ __launch_bounds__(256) void k_diff(const float* __restrict__ dpart, int n,
                                              float* __restrict__ out) {
    int tid = threadIdx.x;
    float s = 0.f;
    for (int i = tid; i < n; i += 256) s += dpart[i];
#pragma unroll
    for (int off = 32; off >= 1; off >>= 1) s += __shfl_down(s, off, 64);
    __shared__ float ws_[4];
    int lane = tid & 63, wvi = tid >> 6;
    if (lane == 0) ws_[wvi] = s;
    __syncthreads();
    if (tid == 0) out[OUT_DIFF] = (ws_[0] + ws_[1] + ws_[2] + ws_[3]) / 16777216.f;
}

extern "C" void kernel_launch(void* const* d_in, const int* in_sizes, int n_in,
                              void* d_out, int out_size, void* d_ws, size_t ws_size,
                              hipStream_t stream) {
    const float* x = (const float*)d_in[0];   // [8,4096,512]
    const float* e = (const float*)d_in[1];   // [512,4096]
    float* out = (float*)d_out;
    float* ws = (float*)d_ws;

    float*  norms = ws + OFF_NORMS;
    float*  et    = ws + OFF_ET;
    float*  dpart = ws + OFF_DP;

    if (ws_size >= (size_t)WS_FAST_FLOATS * 4) {
        float4* part = (float4*)(ws + OFF_PART);
        signed char* xq8 = (signed char*)(ws + OFF_XQ8);
        signed char* eq8 = (signed char*)(ws + OFF_EQ8);
        k_split_et<<<dim3(NEMB / 32, KDIM / 32), dim3(32, 8), 0, stream>>>(e, et, eq8);
        k_norms_et<<<NEMB / 4, 256, 0, stream>>>(et, norms);
        k_quant_x<<<(NROWS * KDIM) / (256 * 4), 256, 0, stream>>>(x, xq8);
        k_mfma_argmin<<<4096, 256, 0, stream>>>(xq8, eq8, norms, part);
        k_refine<<<NROWS / 4, 256, 0, stream>>>(x, et, norms, part, out, dpart);
        k_diff<<<1, 256, 0, stream>>>(dpart, NROWS / 4, out);
    } else {
        float2* part2 = (float2*)(ws + OFF_PART);
        int* idx = (int*)(ws + OFF_IDX);
        k_norms<<<NEMB / 256, 256, 0, stream>>>(e, norms);
        k_transpose<<<dim3(NEMB / 32, KDIM / 32), dim3(32, 8), 0, stream>>>(e, et);
        k_gemm_argmin<<<dim3(NROWS / TMF, NEMB / TNF), 256, 0, stream>>>(x, e, norms, part2);
        k_reduce<<<NROWS / 256, 256, 0, stream>>>(part2, idx, out);
        k_gather<<<NROWS / 16, 256, 0, stream>>>(x, et, idx, out, dpart);
        k_diff<<<1, 256, 0, stream>>>(dpart, NROWS / 16, out);
    }
}

// Round 13
// 197.428 us; speedup vs baseline: 1.4072x; 1.2403x over previous
//
#include <hip/hip_runtime.h>
#include <float.h>

#define NROWS 32768   // B*S = 8*4096
#define KDIM  512
#define NEMB  4096

#define NCB 32        // 128-wide code blocks
#define MARGIN 8.0f   // i8-score candidate margin (~6 sigma; key truncation adds <=0.016)
#define BIAS  1024.0f // keeps pass-1 scores positive -> float bits are uint-order-preserving
#define QSCALE 19.5384615f   // 127/6.5
#define QCLAMP 6.49f
#define QINV2  (-2.0f / (QSCALE * QSCALE))   // score = fmaf(QINV2, dot_int, nrm+BIAS)

// ---- ws layout (float units) ----
#define OFF_NORMS 0u
#define OFF_ET    4096u
#define OFF_PART  (OFF_ET + 2097152u)          // float4 top2: NROWS*NCB
#define OFF_IDX   (OFF_PART + 4194304u)        // fallback only
#define OFF_DP    (OFF_IDX + 32768u)           // 8192 partials
#define OFF_XQ8   (OFF_DP + 8192u)             // i8: NROWS*KDIM bytes = 4,194,304 floats
#define OFF_EQ8   (OFF_XQ8 + 4194304u)         // i8: NEMB*KDIM bytes  =   524,288 floats
#define WS_FAST_FLOATS (OFF_EQ8 + 524288u)     // ~44.2 MB
// ---- out layout (float units) ----
#define OUT_Q    0u
#define OUT_DIFF 16777216u
#define OUT_IDX  16777217u

typedef __attribute__((ext_vector_type(4))) int   i32x4;
typedef __attribute__((ext_vector_type(4))) float f32x4;

static __device__ inline signed char f2q(float v) {
    v = fminf(fmaxf(v, -QCLAMP), QCLAMP);
    return (signed char)__float2int_rn(v * QSCALE);
}
static __device__ inline bool better(float s, int i, float t, int j) {
    return s < t || (s == t && i < j);
}

// ---------------- kernel 1a: norms from original e (fallback path, strided) ----------------
__global__ __launch_bounds__(256) void k_norms(const float* __restrict__ e,
                                               float* __restrict__ norms) {
    int j = blockIdx.x * 256 + threadIdx.x;
    float s = 0.f;
    for (int k = 0; k < KDIM; ++k) {
        float v = e[(size_t)k * NEMB + j];
        s += v * v;
    }
    norms[j] = s;
}

// ---------------- kernel 1b: norms from et (fast path, coalesced rows) ----------------
__global__ __launch_bounds__(256) void k_norms_et(const float* __restrict__ et,
                                                  float* __restrict__ norms) {
    int row = blockIdx.x * 4 + (threadIdx.x >> 6);
    int lane = threadIdx.x & 63;
    const float* er = et + (size_t)row * KDIM + lane * 8;
    float4 v0 = *(const float4*)er;
    float4 v1 = *(const float4*)(er + 4);
    float s = v0.x * v0.x + v0.y * v0.y + v0.z * v0.z + v0.w * v0.w
            + v1.x * v1.x + v1.y * v1.y + v1.z * v1.z + v1.w * v1.w;
#pragma unroll
    for (int off = 1; off < 64; off <<= 1) s += __shfl_xor(s, off, 64);
    if (lane == 0) norms[row] = s;
}

// ---------------- kernel 2: transpose embed + i8 quantize ----------------
__global__ void k_split_et(const float* __restrict__ e, float* __restrict__ et,
                           signed char* __restrict__ eq8) {
    __shared__ float t[32][33];
    int jb = blockIdx.x * 32, kb = blockIdx.y * 32;
    int tx = threadIdx.x, ty = threadIdx.y;
    for (int i = ty; i < 32; i += 8)
        t[i][tx] = e[(size_t)(kb + i) * NEMB + jb + tx];
    __syncthreads();
    for (int i = ty; i < 32; i += 8) {
        float v = t[tx][i];
        size_t o = (size_t)(jb + i) * KDIM + kb + tx;
        et[o] = v;
        eq8[o] = f2q(v);
    }
}

// ---------------- kernel 3: i8 quantize x ----------------
__global__ __launch_bounds__(256) void k_quant_x(const float* __restrict__ x,
                                                 signed char* __restrict__ xq8) {
    size_t i = ((size_t)blockIdx.x * 256 + threadIdx.x) * 4;
    float4 v = *(const float4*)(x + i);
    char4 q;
    q.x = f2q(v.x); q.y = f2q(v.y); q.z = f2q(v.z); q.w = f2q(v.w);
    *(char4*)(xq8 + i) = q;
}

// ---------------- kernel 4: i8 MFMA GEMM + per-128-block TOP-2 ----------------
// 4096 blocks, 256 thr = 4 waves (2 wr x 2 wc), (256,2): VGPR<=128 known-good.
// Block order: cgrp INNER per XCD -> 16 consecutive blocks share one 64KB A-panel
// (xq8 L2-hot after first use); eq8 (2MB) L2-resident.
// SWAPPED operands: code axis lane-local (32 codes/lane). mfma_i32_16x16x64_i8,
// 8 K-steps, dbuf, both-sides 16B-chunk swizzle.
// Epilogue: u32-packed keys (score bits &~127 | 7-bit local code) -> 3-op top-2
// scan + 2-step 32-bit butterfly; in-place in acc (no scratch spill).
__global__ __launch_bounds__(256, 2) void k_mfma_argmin(
        const signed char* __restrict__ xq8, const signed char* __restrict__ eq8,
        const float* __restrict__ norms, float4* __restrict__ part)
{
    __shared__ signed char As[2][128 * 64];   // x rows: 8 KB / buf
    __shared__ signed char Bs[2][256 * 64];   // codes: 16 KB / buf

    const int tid = threadIdx.x;
    const int wv = tid >> 6, ln = tid & 63;
    const int lr = ln & 15, hg = ln >> 4;
    const int wr = wv >> 1, wc = wv & 1;

    // XCD decode, cgrp-inner for A-panel L2 reuse
    const int orig = blockIdx.x;             // 0..4095
    const int xcd = orig & 7;
    const int local = orig >> 3;             // 0..511
    const int cgrp = local & 15;             // inner: 16 col groups share A-panel
    const int rbl = local >> 4;              // 0..31
    const int rb = xcd * 32 + rbl;           // 0..255
    const int row0 = rb * 128, col0 = cgrp * 256;

    // staging source offsets in i8 units (swizzled 16B chunk: cg ^= (r>>1)&3)
    size_t aoff[2], boff[4];
#pragma unroll
    for (int i = 0; i < 2; ++i) {
        int slot = (i * 4 + wv) * 64 + ln;
        int r = slot >> 2;
        int cg = (slot & 3) ^ ((r >> 1) & 3);
        aoff[i] = (size_t)(row0 + r) * KDIM + cg * 16;
    }
#pragma unroll
    for (int i = 0; i < 4; ++i) {
        int slot = (i * 4 + wv) * 64 + ln;
        int r = slot >> 2;
        int cg = (slot & 3) ^ ((r >> 1) & 3);
        boff[i] = (size_t)(col0 + r) * KDIM + cg * 16;
    }

    i32x4 acc[8][4];    // [code-subtile][xrow-subtile]
#pragma unroll
    for (int m = 0; m < 8; ++m)
#pragma unroll
        for (int n = 0; n < 4; ++n) acc[m][n] = (i32x4){0, 0, 0, 0};

#define STAGE(buf, step)                                                            \
    do {                                                                            \
        int k0_ = (step) * 64;                                                      \
        _Pragma("unroll")                                                           \
        for (int i_ = 0; i_ < 2; ++i_)                                              \
            __builtin_amdgcn_global_load_lds(                                       \
                (const __attribute__((address_space(1))) void*)(xq8 + aoff[i_] + k0_), \
                (__attribute__((address_space(3))) void*)&As[buf][(i_ * 4 + wv) * 1024], \
                16, 0, 0);                                                          \
        _Pragma("unroll")                                                           \
        for (int i_ = 0; i_ < 4; ++i_)                                              \
            __builtin_amdgcn_global_load_lds(                                       \
                (const __attribute__((address_space(1))) void*)(eq8 + boff[i_] + k0_), \
                (__attribute__((address_space(3))) void*)&Bs[buf][(i_ * 4 + wv) * 1024], \
                16, 0, 0);                                                          \
    } while (0)

    STAGE(0, 0);
    __syncthreads();
    int cur = 0;
    const int swzB = (hg ^ ((lr >> 1) & 3)) * 16;   // byte offset within 64B row
    for (int step = 0; step < 8; ++step) {
        if (step < 7) STAGE(cur ^ 1, step + 1);
        i32x4 a[8], b[4];
#pragma unroll
        for (int m = 0; m < 8; ++m)     // A-frags = codes (from Bs)
            a[m] = *(const i32x4*)&Bs[cur][(wc * 128 + m * 16 + lr) * 64 + swzB];
#pragma unroll
        for (int n = 0; n < 4; ++n)     // B-frags = x rows (from As)
            b[n] = *(const i32x4*)&As[cur][(wr * 64 + n * 16 + lr) * 64 + swzB];
#pragma unroll
        for (int m = 0; m < 8; ++m)
#pragma unroll
            for (int n = 0; n < 4; ++n)
                acc[m][n] = __builtin_amdgcn_mfma_i32_16x16x64_i8(a[m], b[n], acc[m][n], 0, 0, 0);
        __syncthreads();
        cur ^= 1;
    }
#undef STAGE

    // epilogue A: IN-PLACE i32 dot -> packed u32 key (score bits &~127 | local code)
    const int colbase = col0 + wc * 128;
    const int cbw = cgrp * 2 + wc;
#pragma unroll
    for (int m = 0; m < 8; ++m) {
        float nr[4];
#pragma unroll
        for (int r = 0; r < 4; ++r)
            nr[r] = norms[colbase + m * 16 + hg * 4 + r] + BIAS;
#pragma unroll
        for (int n = 0; n < 4; ++n)
#pragma unroll
            for (int r = 0; r < 4; ++r) {
                unsigned sb = __float_as_uint(
                    fmaf(QINV2, (float)acc[m][n][r], nr[r]));   // > 0 by BIAS
                acc[m][n][r] = (int)((sb & 0xFFFFFF80u)
                                     | (unsigned)(m * 16 + hg * 4 + r));
            }
    }

    // epilogue B: per-xrow TOP-2 over 128 codes via u32 min/max (3 ops/elem)
#pragma unroll
    for (int n = 0; n < 4; ++n) {
        unsigned k0 = 0xFFFFFFFFu, k1 = 0xFFFFFFFFu;
#pragma unroll
        for (int m = 0; m < 8; ++m)
#pragma unroll
            for (int r = 0; r < 4; ++r) {
                unsigned k = (unsigned)acc[m][n][r];
                unsigned t = k < k0 ? k : k0;
                unsigned hi = k > k0 ? k : k0;
                k1 = hi < k1 ? hi : k1;
                k0 = t;
            }
#pragma unroll
        for (int off = 16; off < 64; off <<= 1) {   // butterfly over hg only
            unsigned o0 = __shfl_xor(k0, off, 64);
            unsigned o1 = __shfl_xor(k1, off, 64);
            unsigned t = k0 < o0 ? k0 : o0;
            unsigned hi = k0 > o0 ? k0 : o0;
            unsigned lo1 = k1 < o1 ? k1 : o1;
            k1 = hi < lo1 ? hi : lo1;
            k0 = t;
        }
        if (hg == 0) {
            int row_out = row0 + wr * 64 + n * 16 + lr;
            part[(size_t)row_out * NCB + cbw] =
                make_float4(__uint_as_float(k0 & 0xFFFFFF80u),
                            __int_as_float(colbase + (int)(k0 & 127u)),
                            __uint_as_float(k1 & 0xFFFFFF80u),
                            __int_as_float(colbase + (int)(k1 & 127u)));
        }
    }
}

// ---------------- kernel 5: fused exact refine + quantize gather + diff partial ----------------
__global__ __launch_bounds__(256) void k_refine(const float* __restrict__ x,
                                                const float* __restrict__ et,
                                                const float* __restrict__ norms,
                                                const float4* __restrict__ part,
                                                float* __restrict__ out,
                                                float* __restrict__ dpart) {
    const int row = blockIdx.x * 4 + (threadIdx.x >> 6);
    const int lane = threadIdx.x & 63;

    float xv[8];
    *(float4*)&xv[0] = *(const float4*)(x + (size_t)row * KDIM + lane * 8);
    *(float4*)&xv[4] = *(const float4*)(x + (size_t)row * KDIM + lane * 8 + 4);

    const float4* prow = part + (size_t)row * NCB;
    float m = FLT_MAX;
    for (int cbi = 0; cbi < NCB; ++cbi) m = fminf(m, prow[cbi].x);
    const float thr = m + MARGIN;

    int cnt = 0, only = 0x7FFFFFFF;
    for (int cbi = 0; cbi < NCB; ++cbi) {
        float4 p = prow[cbi];
        if (p.x <= thr) { ++cnt; only = __float_as_int(p.y); }
        if (p.z <= thr) { ++cnt; only = __float_as_int(p.w); }
    }

    int bj;
    if (cnt == 1) {
        bj = only;                                 // unambiguous winner, skip rescoring
    } else {
        float bs = FLT_MAX;
        bj = 0x7FFFFFFF;
        for (int cbi = 0; cbi < NCB; ++cbi) {
            float4 p = prow[cbi];
#pragma unroll
            for (int t = 0; t < 2; ++t) {
                float sh = t ? p.z : p.x;
                int j = __float_as_int(t ? p.w : p.y);
                if (sh <= thr) {                   // wave-uniform branch
                    const float* er = et + (size_t)j * KDIM + lane * 8;
                    float ev[8];
                    *(float4*)&ev[0] = *(const float4*)er;
                    *(float4*)&ev[4] = *(const float4*)(er + 4);
                    float d = 0.f;
#pragma unroll
                    for (int q = 0; q < 8; ++q) d += xv[q] * ev[q];
#pragma unroll
                    for (int off = 1; off < 64; off <<= 1) d += __shfl_xor(d, off, 64);
                    float s = norms[j] - 2.f * d;  // exact fp32 score
                    if (better(s, j, bs, bj)) { bs = s; bj = j; }
                }
            }
        }
    }

    // winner: write quantize row + diff partial
    const float* er = et + (size_t)bj * KDIM + lane * 8;
    float ev[8];
    *(float4*)&ev[0] = *(const float4*)er;
    *(float4*)&ev[4] = *(const float4*)(er + 4);
    float dsum = 0.f;
#pragma unroll
    for (int q = 0; q < 8; ++q) {
        float d = ev[q] - xv[q];
        dsum += d * d;
    }
    *(float4*)(out + OUT_Q + (size_t)row * KDIM + lane * 8) = *(float4*)&ev[0];
    *(float4*)(out + OUT_Q + (size_t)row * KDIM + lane * 8 + 4) = *(float4*)&ev[4];
#pragma unroll
    for (int off = 1; off < 64; off <<= 1) dsum += __shfl_xor(dsum, off, 64);

    __shared__ float ds4[4];
    if (lane == 0) {
        out[OUT_IDX + row] = (float)bj;
        ds4[threadIdx.x >> 6] = dsum;
    }
    __syncthreads();
    if (threadIdx.x == 0)
        dpart[blockIdx.x] = ds4[0] + ds4[1] + ds4[2] + ds4[3];
}

// ---------------- fallback fp32 GEMM-argmin (ws-lean, round-1) ----------------
#define TMF 128
#define TNF 128
#define TKF 16
__global__ __launch_bounds__(256) void k_gemm_argmin(
        const float* __restrict__ x, const float* __restrict__ e,
        const float* __restrict__ norms, float2* __restrict__ part)
{
    __shared__ float xs[TKF][132];
    __shared__ float es[TKF][TNF];
    __shared__ float2 red[TMF][16];

    const int row0 = blockIdx.x * TMF, col0 = blockIdx.y * TNF;
    const int tid = threadIdx.x;
    const int ty = tid >> 4, tx = tid & 15;

    float acc[8][8];
#pragma unroll
    for (int i = 0; i < 8; ++i)
#pragma unroll
        for (int j = 0; j < 8; ++j) acc[i][j] = 0.f;

    for (int k0 = 0; k0 < KDIM; k0 += TKF) {
        __syncthreads();
#pragma unroll
        for (int s = 0; s < 2; ++s) {
            int slot = tid + s * 256;
            int r = slot >> 2, c4 = slot & 3;
            float4 v = *(const float4*)(x + (size_t)(row0 + r) * KDIM + k0 + c4 * 4);
            xs[c4 * 4 + 0][r] = v.x; xs[c4 * 4 + 1][r] = v.y;
            xs[c4 * 4 + 2][r] = v.z; xs[c4 * 4 + 3][r] = v.w;
        }
#pragma unroll
        for (int s = 0; s < 2; ++s) {
            int slot = tid + s * 256;
            int k = slot >> 5, c4 = slot & 31;
            *(float4*)(&es[k][c4 * 4]) =
                *(const float4*)(e + (size_t)(k0 + k) * NEMB + col0 + c4 * 4);
        }
        __syncthreads();
#pragma unroll
        for (int k = 0; k < TKF; ++k) {
            float xv[8], ev[8];
            *(float4*)&xv[0] = *(const float4*)&xs[k][ty * 8];
            *(float4*)&xv[4] = *(const float4*)&xs[k][ty * 8 + 4];
            *(float4*)&ev[0] = *(const float4*)&es[k][tx * 8];
            *(float4*)&ev[4] = *(const float4*)&es[k][tx * 8 + 4];
#pragma unroll
            for (int i = 0; i < 8; ++i)
#pragma unroll
                for (int j = 0; j < 8; ++j) acc[i][j] += xv[i] * ev[j];
        }
    }
    float nrm[8];
#pragma unroll
    for (int j = 0; j < 8; ++j) nrm[j] = norms[col0 + tx * 8 + j];
#pragma unroll
    for (int i = 0; i < 8; ++i) {
        float best = FLT_MAX; int bj = 0;
#pragma unroll
        for (int j = 0; j < 8; ++j) {
            float sc = nrm[j] - 2.f * acc[i][j];
            if (sc < best) { best = sc; bj = tx * 8 + j; }
        }
        red[ty * 8 + i][tx] = make_float2(best, __int_as_float(bj));
    }
    __syncthreads();
    if (tid < TMF) {
        float best = FLT_MAX; int bj = 0;
        for (int t = 0; t < 16; ++t) {
            float2 p = red[tid][t];
            if (p.x < best) { best = p.x; bj = __float_as_int(p.y); }
        }
        part[(size_t)(row0 + tid) * NCB + blockIdx.y] =
            make_float2(best, __int_as_float(col0 + bj));
    }
}

__global__ void k_transpose(const float* __restrict__ e, float* __restrict__ et) {
    __shared__ float t[32][33];
    int jb = blockIdx.x * 32, kb = blockIdx.y * 32;
    int tx = threadIdx.x, ty = threadIdx.y;
    for (int i = ty; i < 32; i += 8)
        t[i][tx] = e[(size_t)(kb + i) * NEMB + jb + tx];
    __syncthreads();
    for (int i = ty; i < 32; i += 8)
        et[(size_t)(jb + i) * KDIM + kb + tx] = t[tx][i];
}

__global__ __launch_bounds__(256) void k_reduce(const float2* __restrict__ part,
                                                int* __restrict__ idx_out,
                                                float* __restrict__ out) {
    int row = blockIdx.x * 256 + threadIdx.x;
    float best = FLT_MAX;
    int bj = 0x7FFFFFFF;
    for (int cbi = 0; cbi < NCB; ++cbi) {
        float2 p = part[(size_t)row * NCB + cbi];
        int c = __float_as_int(p.y);
        if (p.x < best || (p.x == best && c < bj)) { best = p.x; bj = c; }
    }
    idx_out[row] = bj;
    out[OUT_IDX + row] = (float)bj;
}

__global__ __launch_bounds__(256) void k_gather(const float* __restrict__ x,
                                                const float* __restrict__ et,
                                                const int* __restrict__ idx,
                                                float* __restrict__ out,
                                                float* __restrict__ dpart) {
    const int b = blockIdx.x;
    const int tid = threadIdx.x;
    const int row0 = b * 16;
    float s = 0.f;
    for (int i = tid; i < 16 * KDIM; i += 256) {
        int r = i >> 9;
        int k = i & (KDIM - 1);
        int row = row0 + r;
        float q = et[(size_t)idx[row] * KDIM + k];
        float xv = x[(size_t)row * KDIM + k];
        float d = q - xv;
        s += d * d;
        out[OUT_Q + (size_t)row * KDIM + k] = q;
    }
#pragma unroll
    for (int off = 32; off >= 1; off >>= 1) s += __shfl_down(s, off, 64);
    __shared__ float ws_[4];
    int lane = tid & 63, wvi = tid >> 6;
    if (lane == 0) ws_[wvi] = s;
    __syncthreads();
    if (tid == 0) dpart[b] = ws_[0] + ws_[1] + ws_[2] + ws_[3];
}

// ---------------- final diff over n partials ----------------
__global__ __launch_bounds__(256) void k_diff(const float* __restrict__ dpart, int n,
                                              float* __restrict__ out) {
    int tid = threadIdx.x;
    float s = 0.f;
    for (int i = tid; i < n; i += 256) s += dpart[i];
#pragma unroll
    for (int off = 32; off >= 1; off >>= 1) s += __shfl_down(s, off, 64);
    __shared__ float ws_[4];
    int lane = tid & 63, wvi = tid >> 6;
    if (lane == 0) ws_[wvi] = s;
    __syncthreads();
    if (tid == 0) out[OUT_DIFF] = (ws_[0] + ws_[1] + ws_[2] + ws_[3]) / 16777216.f;
}

extern "C" void kernel_launch(void* const* d_in, const int* in_sizes, int n_in,
                              void* d_out, int out_size, void* d_ws, size_t ws_size,
                              hipStream_t stream) {
    const float* x = (const float*)d_in[0];   // [8,4096,512]
    const float* e = (const float*)d_in[1];   // [512,4096]
    float* out = (float*)d_out;
    float* ws = (float*)d_ws;

    float*  norms = ws + OFF_NORMS;
    float*  et    = ws + OFF_ET;
    float*  dpart = ws + OFF_DP;

    if (ws_size >= (size_t)WS_FAST_FLOATS * 4) {
        float4* part = (float4*)(ws + OFF_PART);
        signed char* xq8 = (signed char*)(ws + OFF_XQ8);
        signed char* eq8 = (signed char*)(ws + OFF_EQ8);
        k_split_et<<<dim3(NEMB / 32, KDIM / 32), dim3(32, 8), 0, stream>>>(e, et, eq8);
        k_norms_et<<<NEMB / 4, 256, 0, stream>>>(et, norms);
        k_quant_x<<<(NROWS * KDIM) / (256 * 4), 256, 0, stream>>>(x, xq8);
        k_mfma_argmin<<<4096, 256, 0, stream>>>(xq8, eq8, norms, part);
        k_refine<<<NROWS / 4, 256, 0, stream>>>(x, et, norms, part, out, dpart);
        k_diff<<<1, 256, 0, stream>>>(dpart, NROWS / 4, out);
    } else {
        float2* part2 = (float2*)(ws + OFF_PART);
        int* idx = (int*)(ws + OFF_IDX);
        k_norms<<<NEMB / 256, 256, 0, stream>>>(e, norms);
        k_transpose<<<dim3(NEMB / 32, KDIM / 32), dim3(32, 8), 0, stream>>>(e, et);
        k_gemm_argmin<<<dim3(NROWS / TMF, NEMB / TNF), 256, 0, stream>>>(x, e, norms, part2);
        k_reduce<<<NROWS / 256, 256, 0, stream>>>(part2, idx, out);
        k_gather<<<NROWS / 16, 256, 0, stream>>>(x, et, idx, out, dpart);
        k_diff<<<1, 256, 0, stream>>>(dpart, NROWS / 16, out);
    }
}